// Round 15
// baseline (36.095 us; speedup 1.0000x reference)
//
#include <hip/hip_runtime.h>
#include <hip/hip_bf16.h>
#include <stdint.h>

typedef __attribute__((ext_vector_type(8))) short short8;
typedef __attribute__((ext_vector_type(4))) float f32x4;

__device__ __forceinline__ unsigned int f2bf(float f) {
    unsigned int u = __float_as_uint(f);
    return (u + 0x7fffu + ((u >> 16) & 1u)) >> 16;   // RNE fp32 -> bf16
}

// ---- kernel 1: fp32 -> bf16 in FRAGMENT-NATIVE layout + row squared norms ----
// Element (row,k) at byte (row>>4)*4096 + (k>>3)*256 + (row&15)*16 + (k&7)*2.
__global__ void prep_kernel(const float* __restrict__ emb,
                            unsigned short* __restrict__ ebs,
                            float* __restrict__ sq, int n) {
    int t = threadIdx.x;
    int row = blockIdx.x * 16 + (t >> 4);
    int c   = t & 15;
    if (row >= n) return;
    const float* src = emb + (size_t)row * 128 + c * 8;
    float4 f0 = *reinterpret_cast<const float4*>(src);
    float4 f1 = *reinterpret_cast<const float4*>(src + 4);
    uint4 wv;
    wv.x = f2bf(f0.x) | (f2bf(f0.y) << 16);
    wv.y = f2bf(f0.z) | (f2bf(f0.w) << 16);
    wv.z = f2bf(f1.x) | (f2bf(f1.y) << 16);
    wv.w = f2bf(f1.z) | (f2bf(f1.w) << 16);
    size_t byte = (size_t)(row >> 4) * 4096 + c * 256 + (row & 15) * 16;
    *reinterpret_cast<uint4*>(reinterpret_cast<char*>(ebs) + byte) = wv;
    float p = f0.x*f0.x + f0.y*f0.y + f0.z*f0.z + f0.w*f0.w
            + f1.x*f1.x + f1.y*f1.y + f1.z*f1.z + f1.w*f1.w;
    #pragma unroll
    for (int off = 1; off < 16; off <<= 1) p += __shfl_xor(p, off);
    if (c == 0) sq[row] = p;
}

// ---- kernel 2: ONE 64x64 tile per block, batched register loads, no LDS,
// no atomics. Epilogue skips the sqrt chain when the whole wave provably
// contributes zero (different labels && d2 >= 1  =>  max(1-ds,0) == 0). ----
__launch_bounds__(256, 4)
__global__ void loss_kernel(const unsigned short* __restrict__ ebs,
                            const int* __restrict__ labels,
                            const float* __restrict__ sq,
                            float* __restrict__ partials) {
    __shared__ float wsum[4];

    // triangular decode: block id -> (bi <= bj)
    int id = blockIdx.x;
    int bj = (int)((sqrtf(8.0f * (float)id + 1.0f) - 1.0f) * 0.5f);
    while (((bj + 1) * (bj + 2)) >> 1 <= id) ++bj;
    while (((bj * (bj + 1)) >> 1) > id) --bj;
    int bi = id - ((bj * (bj + 1)) >> 1);
    int rowBase = bi << 6, colBase = bj << 6;
    bool offdiag = (bi != bj);

    int t = threadIdx.x, lane = t & 63, w = t >> 6;
    int wr = (w & 1) << 5, wc = (w >> 1) << 5;   // 2x2 waves of 32x32
    int fr = lane & 15, kg = lane >> 4, lo = lane << 4;

    const char* base = reinterpret_cast<const char*>(ebs);
    const char* gA = base + (size_t)((rowBase + wr) >> 4) * 4096;
    const char* gB = base + (size_t)((colBase + wc) >> 4) * 4096;

    // batch-issue ALL fragment loads first (16 x coalesced 1KB wave-loads)
    short8 a[2][4], b[2][4];
    #pragma unroll
    for (int kk = 0; kk < 4; ++kk) {
        a[0][kk] = *reinterpret_cast<const short8*>(gA        + kk * 1024 + lo);
        a[1][kk] = *reinterpret_cast<const short8*>(gA + 4096 + kk * 1024 + lo);
        b[0][kk] = *reinterpret_cast<const short8*>(gB        + kk * 1024 + lo);
        b[1][kk] = *reinterpret_cast<const short8*>(gB + 4096 + kk * 1024 + lo);
    }

    // metadata loads (independent of fragments)
    float4 sqi[2]; int4 labi[2];
    #pragma unroll
    for (int m = 0; m < 2; ++m) {
        int irb = rowBase + wr + m * 16 + kg * 4;
        sqi[m]  = *reinterpret_cast<const float4*>(sq + irb);
        labi[m] = *reinterpret_cast<const int4*>(labels + irb);
    }
    float sqj0  = sq[colBase + wc + fr];
    float sqj1  = sq[colBase + wc + 16 + fr];
    int   labj0 = labels[colBase + wc + fr];
    int   labj1 = labels[colBase + wc + 16 + fr];

    f32x4 acc[2][2];
    const f32x4 zero = {0.0f, 0.0f, 0.0f, 0.0f};
    acc[0][0] = zero; acc[0][1] = zero; acc[1][0] = zero; acc[1][1] = zero;

    #pragma unroll
    for (int kk = 0; kk < 4; ++kk) {
        acc[0][0] = __builtin_amdgcn_mfma_f32_16x16x32_bf16(a[0][kk], b[0][kk], acc[0][0], 0, 0, 0);
        acc[0][1] = __builtin_amdgcn_mfma_f32_16x16x32_bf16(a[0][kk], b[1][kk], acc[0][1], 0, 0, 0);
        acc[1][0] = __builtin_amdgcn_mfma_f32_16x16x32_bf16(a[1][kk], b[0][kk], acc[1][0], 0, 0, 0);
        acc[1][1] = __builtin_amdgcn_mfma_f32_16x16x32_bf16(a[1][kk], b[1][kk], acc[1][1], 0, 0, 0);
    }

    float l0 = 0.0f, l1 = 0.0f, l2 = 0.0f, l3 = 0.0f;

    // epilogue: C/D layout col=lane&15, row=(lane>>4)*4+reg.
    // Wave-level skip: if no lane is (pred && (same || d2 < 1)), every lane's
    // contribution is exactly 0 -> branch over both sqrts.
    #define EPI(PREDEXPR)                                                      \
    {                                                                          \
        _Pragma("unroll")                                                      \
        for (int m = 0; m < 2; ++m) {                                          \
            int irb = wr + m * 16 + kg * 4;                                    \
            _Pragma("unroll")                                                  \
            for (int nn = 0; nn < 2; ++nn) {                                   \
                float sj = nn ? sqj1 : sqj0;                                   \
                int   lj = nn ? labj1 : labj0;                                 \
                int   jc = wc + nn * 16 + fr; (void)jc;                        \
                _Pragma("unroll")                                              \
                for (int r4 = 0; r4 < 4; ++r4) {                               \
                    int ir = irb + r4; (void)ir;                               \
                    bool pred = (PREDEXPR);                                    \
                    float si = (r4 == 0) ? sqi[m].x : (r4 == 1) ? sqi[m].y     \
                             : (r4 == 2) ? sqi[m].z : sqi[m].w;                \
                    int   li = (r4 == 0) ? labi[m].x : (r4 == 1) ? labi[m].y   \
                             : (r4 == 2) ? labi[m].z : labi[m].w;              \
                    float d2   = fmaf(-2.0f, acc[m][nn][r4], si + sj);         \
                    bool  same = (li == lj);                                   \
                    bool  need = pred && (same || (d2 < 1.0f));                \
                    if (__any(need)) {                                         \
                        float dist = __builtin_amdgcn_sqrtf(fmaxf(d2, 0.0f));  \
                        float ds   = __builtin_amdgcn_sqrtf(dist + 1e-7f);     \
                        float v    = same ? ds : fmaxf(1.0f - ds, 0.0f);       \
                        v = pred ? v : 0.0f;                                   \
                        if      (r4 == 0) l0 += v;                             \
                        else if (r4 == 1) l1 += v;                             \
                        else if (r4 == 2) l2 += v;                             \
                        else              l3 += v;                             \
                    }                                                          \
                }                                                              \
            }                                                                  \
        }                                                                      \
    }
    if (offdiag) EPI(true)
    else         EPI(jc > ir)
    #undef EPI

    float local = (l0 + l1) + (l2 + l3);
    #pragma unroll
    for (int off = 32; off > 0; off >>= 1) local += __shfl_down(local, off);
    if (lane == 0) wsum[w] = local;
    __syncthreads();
    if (t == 0)
        partials[blockIdx.x] = (wsum[0] + wsum[1]) + (wsum[2] + wsum[3]);
}

// ---- kernel 3: deterministic tree-reduce of partials -> scalar output ----
__launch_bounds__(1024)
__global__ void reduce_kernel(const float* __restrict__ partials, int nBlocks,
                              float* __restrict__ out, float inv_pairs) {
    __shared__ float ws[16];
    int t = threadIdx.x, lane = t & 63, w = t >> 6;
    float s = 0.0f;
    for (int i = t; i < nBlocks; i += 1024) s += partials[i];
    #pragma unroll
    for (int off = 32; off > 0; off >>= 1) s += __shfl_down(s, off);
    if (lane == 0) ws[w] = s;
    __syncthreads();
    if (w == 0) {
        float v = (lane < 16) ? ws[lane] : 0.0f;
        #pragma unroll
        for (int off = 8; off > 0; off >>= 1) v += __shfl_down(v, off);
        if (lane == 0) out[0] = v * inv_pairs;
    }
}

extern "C" void kernel_launch(void* const* d_in, const int* in_sizes, int n_in,
                              void* d_out, int out_size, void* d_ws, size_t ws_size,
                              hipStream_t stream) {
    const float* emb   = (const float*)d_in[0];
    const int*  labels = (const int*)d_in[1];
    int n  = in_sizes[1];          // 8192
    int nt = n >> 6;               // 64-row tiles -> 128

    float*          sq       = (float*)((char*)d_ws + 256);
    unsigned short* ebs      = (unsigned short*)((char*)d_ws + 65536);
    size_t          ebsBytes = (size_t)n * 128 * 2;
    float*          partials = (float*)((char*)d_ws + 65536 + ebsBytes);

    prep_kernel<<<n / 16, 256, 0, stream>>>(emb, ebs, sq, n);

    int nBlocks = nt * (nt + 1) / 2;   // 8256 uniform single-tile blocks
    loss_kernel<<<nBlocks, 256, 0, stream>>>(ebs, labels, sq, partials);

    float inv_pairs = (float)(2.0 / ((double)n * (double)(n - 1)));
    reduce_kernel<<<1, 1024, 0, stream>>>(partials, nBlocks, (float*)d_out, inv_pairs);
}

// Round 16
// 30.451 us; speedup vs baseline: 1.1854x; 1.1854x over previous
//
#include <hip/hip_runtime.h>
#include <hip/hip_bf16.h>
#include <stdint.h>

typedef __attribute__((ext_vector_type(8))) short short8;
typedef __attribute__((ext_vector_type(4))) float f32x4;

__device__ __forceinline__ unsigned int f2bf(float f) {
    unsigned int u = __float_as_uint(f);
    return (u + 0x7fffu + ((u >> 16) & 1u)) >> 16;   // RNE fp32 -> bf16
}

// ---- kernel 1: fp32 -> bf16 in FRAGMENT-NATIVE layout + row squared norms ----
// Element (row,k) at byte (row>>4)*4096 + (k>>3)*256 + (row&15)*16 + (k&7)*2.
__global__ void prep_kernel(const float* __restrict__ emb,
                            unsigned short* __restrict__ ebs,
                            float* __restrict__ sq, int n) {
    int t = threadIdx.x;
    int row = blockIdx.x * 16 + (t >> 4);
    int c   = t & 15;
    if (row >= n) return;
    const float* src = emb + (size_t)row * 128 + c * 8;
    float4 f0 = *reinterpret_cast<const float4*>(src);
    float4 f1 = *reinterpret_cast<const float4*>(src + 4);
    uint4 wv;
    wv.x = f2bf(f0.x) | (f2bf(f0.y) << 16);
    wv.y = f2bf(f0.z) | (f2bf(f0.w) << 16);
    wv.z = f2bf(f1.x) | (f2bf(f1.y) << 16);
    wv.w = f2bf(f1.z) | (f2bf(f1.w) << 16);
    size_t byte = (size_t)(row >> 4) * 4096 + c * 256 + (row & 15) * 16;
    *reinterpret_cast<uint4*>(reinterpret_cast<char*>(ebs) + byte) = wv;
    float p = f0.x*f0.x + f0.y*f0.y + f0.z*f0.z + f0.w*f0.w
            + f1.x*f1.x + f1.y*f1.y + f1.z*f1.z + f1.w*f1.w;
    #pragma unroll
    for (int off = 1; off < 16; off <<= 1) p += __shfl_xor(p, off);
    if (c == 0) sq[row] = p;
}

// ---- kernel 2: 128x128 tile per block. A batch-loaded to regs (no intra-block
// redundancy); B staged once to LDS (one barrier), read as conflict-free
// ds_read_b128. Wave = 32-row strip x 128 cols, 4 sequential 32-col subtiles.
// No atomics: partials[] + separate reduce. ----
__launch_bounds__(256, 4)
__global__ void loss_kernel(const unsigned short* __restrict__ ebs,
                            const int* __restrict__ labels,
                            const float* __restrict__ sq,
                            float* __restrict__ partials) {
    __shared__ __align__(16) char Bs[32768];
    __shared__ float wsum[4];

    // triangular decode: block id -> (bi <= bj)
    int id = blockIdx.x;
    int bj = (int)((sqrtf(8.0f * (float)id + 1.0f) - 1.0f) * 0.5f);
    while (((bj + 1) * (bj + 2)) >> 1 <= id) ++bj;
    while (((bj * (bj + 1)) >> 1) > id) --bj;
    int bi = id - ((bj * (bj + 1)) >> 1);
    int rowBase = bi << 7, colBase = bj << 7;
    bool offdiag = (bi != bj);

    int t = threadIdx.x, lane = t & 63, w = t >> 6;
    int wr = w << 5;                      // wave's 32-row strip: 0,32,64,96
    int fr = lane & 15, kg = lane >> 4, lo = lane << 4;

    const char* base = reinterpret_cast<const char*>(ebs);

    // stage B band (contiguous 32 KB in frag-native layout) into LDS
    {
        const char* gB = base + (size_t)(colBase >> 4) * 4096;
        int thrOff = t << 4;
        #pragma unroll
        for (int it = 0; it < 8; ++it) {
            int off = (it << 12) + thrOff;
            __builtin_amdgcn_global_load_lds(
                (const __attribute__((address_space(1))) void*)(gB + off),
                (__attribute__((address_space(3))) void*)(Bs + off), 16, 0, 0);
        }
    }

    // A fragments for this wave's strip: batched coalesced 1KB wave-loads
    const char* gA = base + (size_t)((rowBase + wr) >> 4) * 4096;
    short8 a[2][4];
    #pragma unroll
    for (int m = 0; m < 2; ++m)
        #pragma unroll
        for (int kk = 0; kk < 4; ++kk)
            a[m][kk] = *reinterpret_cast<const short8*>(gA + m * 4096 + kk * 1024 + lo);

    // block-invariant row norms / labels for this wave's strip
    float4 sqi[2]; int4 labi[2];
    #pragma unroll
    for (int m = 0; m < 2; ++m) {
        int irb = rowBase + wr + m * 16 + kg * 4;
        sqi[m]  = *reinterpret_cast<const float4*>(sq + irb);
        labi[m] = *reinterpret_cast<const int4*>(labels + irb);
    }

    __syncthreads();   // B staged

    float l0 = 0.0f, l1 = 0.0f, l2 = 0.0f, l3 = 0.0f;

    #pragma unroll
    for (int s = 0; s < 4; ++s) {         // 32-col subtiles
        int cs = s << 5;
        // diagonal block: subtile entirely below the diagonal -> skip (uniform)
        if (!offdiag && cs + 32 <= wr) continue;

        // B fragments from LDS (8x conflict-free ds_read_b128)
        short8 b[2][4];
        #pragma unroll
        for (int nn = 0; nn < 2; ++nn)
            #pragma unroll
            for (int kk = 0; kk < 4; ++kk)
                b[nn][kk] = *reinterpret_cast<const short8*>(
                    Bs + ((cs >> 4) + nn) * 4096 + kk * 1024 + lo);

        f32x4 acc[2][2];
        const f32x4 zero = {0.0f, 0.0f, 0.0f, 0.0f};
        acc[0][0] = zero; acc[0][1] = zero; acc[1][0] = zero; acc[1][1] = zero;
        #pragma unroll
        for (int kk = 0; kk < 4; ++kk) {
            acc[0][0] = __builtin_amdgcn_mfma_f32_16x16x32_bf16(a[0][kk], b[0][kk], acc[0][0], 0, 0, 0);
            acc[0][1] = __builtin_amdgcn_mfma_f32_16x16x32_bf16(a[0][kk], b[1][kk], acc[0][1], 0, 0, 0);
            acc[1][0] = __builtin_amdgcn_mfma_f32_16x16x32_bf16(a[1][kk], b[0][kk], acc[1][0], 0, 0, 0);
            acc[1][1] = __builtin_amdgcn_mfma_f32_16x16x32_bf16(a[1][kk], b[1][kk], acc[1][1], 0, 0, 0);
        }

        float sqj0  = sq[colBase + cs + fr];
        float sqj1  = sq[colBase + cs + 16 + fr];
        int   labj0 = labels[colBase + cs + fr];
        int   labj1 = labels[colBase + cs + 16 + fr];

        bool fullTile = offdiag || (cs >= wr + 32);

        // epilogue: C/D layout col=lane&15, row=(lane>>4)*4+reg.
        // Wave-skip: different labels && d2>=1 -> contribution exactly 0.
        #define EPI(PREDEXPR)                                                  \
        {                                                                      \
            _Pragma("unroll")                                                  \
            for (int m = 0; m < 2; ++m) {                                      \
                int irb = wr + m * 16 + kg * 4;                                \
                _Pragma("unroll")                                              \
                for (int nn = 0; nn < 2; ++nn) {                               \
                    float sj = nn ? sqj1 : sqj0;                               \
                    int   lj = nn ? labj1 : labj0;                             \
                    int   jc = cs + nn * 16 + fr; (void)jc;                    \
                    _Pragma("unroll")                                          \
                    for (int r4 = 0; r4 < 4; ++r4) {                           \
                        int ir = irb + r4; (void)ir;                           \
                        bool pred = (PREDEXPR);                                \
                        float si = (r4 == 0) ? sqi[m].x : (r4 == 1) ? sqi[m].y \
                                 : (r4 == 2) ? sqi[m].z : sqi[m].w;            \
                        int   li = (r4 == 0) ? labi[m].x : (r4 == 1) ? labi[m].y \
                                 : (r4 == 2) ? labi[m].z : labi[m].w;          \
                        float d2   = fmaf(-2.0f, acc[m][nn][r4], si + sj);     \
                        bool  same = (li == lj);                               \
                        bool  need = pred && (same || (d2 < 1.0f));            \
                        if (__any(need)) {                                     \
                            float dist = __builtin_amdgcn_sqrtf(fmaxf(d2, 0.0f)); \
                            float ds   = __builtin_amdgcn_sqrtf(dist + 1e-7f); \
                            float v    = same ? ds : fmaxf(1.0f - ds, 0.0f);   \
                            v = pred ? v : 0.0f;                               \
                            if      (r4 == 0) l0 += v;                         \
                            else if (r4 == 1) l1 += v;                         \
                            else if (r4 == 2) l2 += v;                         \
                            else              l3 += v;                         \
                        }                                                      \
                    }                                                          \
                }                                                              \
            }                                                                  \
        }
        if (fullTile) EPI(true)
        else          EPI(jc > ir)
        #undef EPI
    }

    float local = (l0 + l1) + (l2 + l3);
    #pragma unroll
    for (int off = 32; off > 0; off >>= 1) local += __shfl_down(local, off);
    if (lane == 0) wsum[w] = local;
    __syncthreads();
    if (t == 0)
        partials[blockIdx.x] = (wsum[0] + wsum[1]) + (wsum[2] + wsum[3]);
}

// ---- kernel 3: deterministic tree-reduce of partials -> scalar output ----
__launch_bounds__(1024)
__global__ void reduce_kernel(const float* __restrict__ partials, int nBlocks,
                              float* __restrict__ out, float inv_pairs) {
    __shared__ float ws[16];
    int t = threadIdx.x, lane = t & 63, w = t >> 6;
    float s = 0.0f;
    for (int i = t; i < nBlocks; i += 1024) s += partials[i];
    #pragma unroll
    for (int off = 32; off > 0; off >>= 1) s += __shfl_down(s, off);
    if (lane == 0) ws[w] = s;
    __syncthreads();
    if (w == 0) {
        float v = (lane < 16) ? ws[lane] : 0.0f;
        #pragma unroll
        for (int off = 8; off > 0; off >>= 1) v += __shfl_down(v, off);
        if (lane == 0) out[0] = v * inv_pairs;
    }
}

extern "C" void kernel_launch(void* const* d_in, const int* in_sizes, int n_in,
                              void* d_out, int out_size, void* d_ws, size_t ws_size,
                              hipStream_t stream) {
    const float* emb   = (const float*)d_in[0];
    const int*  labels = (const int*)d_in[1];
    int n  = in_sizes[1];          // 8192
    int nt = n >> 7;               // 128-row tiles -> 64

    float*          sq       = (float*)((char*)d_ws + 256);
    unsigned short* ebs      = (unsigned short*)((char*)d_ws + 65536);
    size_t          ebsBytes = (size_t)n * 128 * 2;
    float*          partials = (float*)((char*)d_ws + 65536 + ebsBytes);

    prep_kernel<<<n / 16, 256, 0, stream>>>(emb, ebs, sq, n);

    int nBlocks = nt * (nt + 1) / 2;   // 2080 uniform 128x128 blocks
    loss_kernel<<<nBlocks, 256, 0, stream>>>(ebs, labels, sq, partials);

    float inv_pairs = (float)(2.0 / ((double)n * (double)(n - 1)));
    reduce_kernel<<<1, 1024, 0, stream>>>(partials, nBlocks, (float*)d_out, inv_pairs);
}